// Round 1
// baseline (220.397 us; speedup 1.0000x reference)
//
#include <hip/hip_runtime.h>

// out[s,b,d] = x[s,b,d] + ((S-1)/2 - s), S=4096, B=4, D=2048 (fp32).
// Memory-bound elementwise: float4 loads/stores, one thread per float4.
// B*D = 8192 floats per s-row = 2048 float4s => s = i4 >> 11.

__global__ __launch_bounds__(256) void rpe_kernel(const float4* __restrict__ x,
                                                  float4* __restrict__ out,
                                                  int n4) {
    int i = blockIdx.x * blockDim.x + threadIdx.x;
    if (i >= n4) return;
    int s = i >> 11;                      // i4 / 2048 float4s-per-row
    float bias = 2047.5f - (float)s;      // (4096-1)*0.5 - s
    float4 v = x[i];
    v.x += bias;
    v.y += bias;
    v.z += bias;
    v.w += bias;
    out[i] = v;
}

extern "C" void kernel_launch(void* const* d_in, const int* in_sizes, int n_in,
                              void* d_out, int out_size, void* d_ws, size_t ws_size,
                              hipStream_t stream) {
    const float4* x = (const float4*)d_in[0];
    float4* out = (float4*)d_out;
    int n4 = in_sizes[0] / 4;             // 33,554,432 / 4 = 8,388,608
    int threads = 256;
    int blocks = (n4 + threads - 1) / threads;  // 32768
    rpe_kernel<<<blocks, threads, 0, stream>>>(x, out, n4);
}

// Round 3
// 217.099 us; speedup vs baseline: 1.0152x; 1.0152x over previous
//
#include <hip/hip_runtime.h>

// out[s,b,d] = x[s,b,d] + (2047.5 - s), shape (4096, 4, 2048) fp32.
// Pure streaming, zero reuse: 268 MB total traffic, floor ~40 us @ 6.7 TB/s
// (harness fill dispatches measured 6.7 TB/s on this box).
// 4 float4s per thread, stride-256 interleave (perfect coalescing),
// nontemporal hints to avoid cache-allocate on a zero-reuse stream.
// Use clang ext_vector_type: __builtin_nontemporal_* rejects HIP_vector_type.
// B*D = 8192 floats per s-row = 2048 float4s => s = i4 >> 11.

typedef float fvec4 __attribute__((ext_vector_type(4)));

__global__ __launch_bounds__(256) void rpe_kernel(const fvec4* __restrict__ x,
                                                  fvec4* __restrict__ out) {
    int base = blockIdx.x * 1024 + threadIdx.x;

    fvec4 v[4];
    int idx[4];
    #pragma unroll
    for (int k = 0; k < 4; ++k) {
        idx[k] = base + k * 256;
        v[k] = __builtin_nontemporal_load(&x[idx[k]]);
    }
    #pragma unroll
    for (int k = 0; k < 4; ++k) {
        float bias = 2047.5f - (float)(idx[k] >> 11);
        v[k] += bias;   // ext_vector: scalar broadcast add
        __builtin_nontemporal_store(v[k], &out[idx[k]]);
    }
}

extern "C" void kernel_launch(void* const* d_in, const int* in_sizes, int n_in,
                              void* d_out, int out_size, void* d_ws, size_t ws_size,
                              hipStream_t stream) {
    const fvec4* x = (const fvec4*)d_in[0];
    fvec4* out = (fvec4*)d_out;
    int n4 = in_sizes[0] / 4;                 // 8,388,608, divisible by 1024
    int blocks = n4 / 1024;                   // 8192 blocks x 256 threads x 4 float4
    rpe_kernel<<<blocks, 256, 0, stream>>>(x, out);
}